// Round 11
// baseline (89.303 us; speedup 1.0000x reference)
//
#include <hip/hip_runtime.h>
#include <hip/hip_bf16.h>

#define NN 8192
#define D_IN 128
#define D_OUT 64
#define GAT_ALPHA 0.2f
#define LOG2E 1.4426950408889634f

typedef __attribute__((ext_vector_type(4))) float f32x4;
typedef __attribute__((ext_vector_type(8))) short short8;
typedef __attribute__((ext_vector_type(4))) int i32x4;

static __device__ __forceinline__ unsigned short f32_bf16(float f) {
    unsigned u = __builtin_bit_cast(unsigned, f);
    u += 0x7fffu + ((u >> 16) & 1u);   // round-to-nearest-even
    return (unsigned short)(u >> 16);
}

// ---- Kernel 1: wh = h@w; wh1p/wh2p (x log2e); whB = K-blocked bf16 wh^T ----
// whB[j>>3][dim][j&7]: element (dim, j) at whB[(j>>3)*512 + dim*8 + (j&7)]
__global__ __launch_bounds__(256) void gat_prep(
    const float* __restrict__ h, const float* __restrict__ w,
    const float* __restrict__ a,
    unsigned short* __restrict__ whB, float* __restrict__ wh1p,
    float* __restrict__ wh2p)
{
    __shared__ float hs[16 * 128];
    __shared__ float whs[16][64];
    const int t = threadIdx.x;
    const int i0 = blockIdx.x * 16;

    const float* hsrc = h + (size_t)i0 * D_IN;
    *(float4*)(hs + t * 8)     = *(const float4*)(hsrc + t * 8);
    *(float4*)(hs + t * 8 + 4) = *(const float4*)(hsrc + t * 8 + 4);
    __syncthreads();

    const int r  = t >> 4;          // local row 0..15
    const int og = (t & 15) * 4;    // 4 output dims
    f32x4 acc = {0.f, 0.f, 0.f, 0.f};
    for (int k = 0; k < D_IN; ++k) {
        float hv = hs[r * 128 + k];
        float4 wv = *(const float4*)(w + k * D_OUT + og);
        acc[0] += hv * wv.x; acc[1] += hv * wv.y;
        acc[2] += hv * wv.z; acc[3] += hv * wv.w;
    }
    whs[r][og]     = acc[0];
    whs[r][og + 1] = acc[1];
    whs[r][og + 2] = acc[2];
    whs[r][og + 3] = acc[3];

    float p1 = acc[0]*a[og] + acc[1]*a[og+1] + acc[2]*a[og+2] + acc[3]*a[og+3];
    float p2 = acc[0]*a[64+og] + acc[1]*a[64+og+1] + acc[2]*a[64+og+2] + acc[3]*a[64+og+3];
    #pragma unroll
    for (int m = 1; m < 16; m <<= 1) {
        p1 += __shfl_xor(p1, m);
        p2 += __shfl_xor(p2, m);
    }
    if ((t & 15) == 0) {
        wh1p[i0 + r] = p1 * LOG2E;
        wh2p[i0 + r] = p2 * LOG2E;
    }
    __syncthreads();

    {
        const int half = t >> 7;         // which 8-row group
        const int dim  = (t >> 1) & 63;
        const int e0   = (t & 1) * 4;
        ushort4 v;
        v.x = f32_bf16(whs[half * 8 + e0 + 0][dim]);
        v.y = f32_bf16(whs[half * 8 + e0 + 1][dim]);
        v.z = f32_bf16(whs[half * 8 + e0 + 2][dim]);
        v.w = f32_bf16(whs[half * 8 + e0 + 3][dim]);
        *(ushort4*)(whB + (size_t)(i0 / 8 + half) * 512 + dim * 8 + e0) = v;
    }
}

static __device__ __forceinline__ short8 pack8_bf16(const float* p) {
    union { unsigned int u[4]; short8 s; } r;
    asm("v_cvt_pk_bf16_f32 %0, %1, %2" : "=v"(r.u[0]) : "v"(p[0]), "v"(p[1]));
    asm("v_cvt_pk_bf16_f32 %0, %1, %2" : "=v"(r.u[1]) : "v"(p[2]), "v"(p[3]));
    asm("v_cvt_pk_bf16_f32 %0, %1, %2" : "=v"(r.u[2]) : "v"(p[4]), "v"(p[5]));
    asm("v_cvt_pk_bf16_f32 %0, %1, %2" : "=v"(r.u[3]) : "v"(p[6]), "v"(p[7]));
    return r.s;
}

// ---- Kernel 2 (fused): NT-stream 16 adj rows -> per-lane byte pack (no
// cross-lane, no divergence, 8 loads batched in flight) -> masks in LDS ->
// fused softmax + att@wh + bias + elu. 512 blocks x 512 thr (8 waves).
// Wave wv packs rows {2wv, 2wv+1}; computes cols [wv*1024,(wv+1)*1024).
__global__ __launch_bounds__(512) void gat_fused(
    const int* __restrict__ adj, const unsigned short* __restrict__ whB,
    const float* __restrict__ wh1p, const float* __restrict__ wh2p,
    const float* __restrict__ bias, float* __restrict__ out)
{
    __shared__ alignas(16) char smem[33792];
    unsigned int (*bmlds)[260] = (unsigned int(*)[260])smem;   // [16][260] = 16.6 KB
    float (*nums)[16][64] = (float(*)[16][64])smem;            // [8][16][64] = 32 KB (overlay)
    float (*dens)[16] = (float(*)[16])(smem + 32768);          // [8][16]

    const int t    = threadIdx.x;
    const int wv   = t >> 6;
    const int lane = t & 63;
    const int il   = lane & 15;
    const int kg   = lane >> 4;
    const int r0   = blockIdx.x * 16;

    // ---- phase 1: NT-stream rows -> 1-bit masks in LDS ----
    // chunk ch covers ints [ch*512,(ch+1)*512); lane packs ints ch*512+lane*8
    // ..+7 into mask byte row*1040 + ch*64 + lane. Pure per-lane, branch-free.
    #pragma unroll
    for (int rr = 0; rr < 2; ++rr) {
        const int row = wv * 2 + rr;
        const int* src = adj + (size_t)(r0 + row) * NN;
        unsigned char* dst = (unsigned char*)smem + row * 1040 + lane;
        #pragma unroll
        for (int b = 0; b < 4; ++b) {
            i32x4 v[8];
            #pragma unroll
            for (int c = 0; c < 4; ++c) {
                const i32x4* p = (const i32x4*)(src + (b * 4 + c) * 512 + lane * 8);
                v[2 * c]     = __builtin_nontemporal_load(p);
                v[2 * c + 1] = __builtin_nontemporal_load(p + 1);
            }
            #pragma unroll
            for (int c = 0; c < 4; ++c) {
                i32x4 a0 = v[2 * c], a1 = v[2 * c + 1];
                unsigned bb =
                    (unsigned)(a0.x > 0)        | ((unsigned)(a0.y > 0) << 1) |
                    ((unsigned)(a0.z > 0) << 2) | ((unsigned)(a0.w > 0) << 3) |
                    ((unsigned)(a1.x > 0) << 4) | ((unsigned)(a1.y > 0) << 5) |
                    ((unsigned)(a1.z > 0) << 6) | ((unsigned)(a1.w > 0) << 7);
                dst[(b * 4 + c) * 64] = (unsigned char)bb;
            }
        }
    }
    __syncthreads();

    // ---- phase 2: compute (no barriers; masks from LDS, whB from L2) ----
    const float c = wh1p[r0 + il];
    const int shk = kg * 8;

    f32x4 acc0 = {0,0,0,0}, acc1 = {0,0,0,0}, acc2 = {0,0,0,0}, acc3 = {0,0,0,0};
    float den = 0.f;

    #pragma unroll 4
    for (int n = 0; n < 32; ++n) {
        const int jd = wv * 32 + n;      // dword (32-col) index
        const int j0 = jd * 32;          // global col

        unsigned int m0 = bmlds[il][jd] >> shk;
        float4 W0 = *(const float4*)(wh2p + j0 + kg * 8);
        float4 W1 = *(const float4*)(wh2p + j0 + kg * 8 + 4);

        const unsigned short* bb = whB + (size_t)(j0 / 8 + kg) * 512 + il * 8;
        short8 b0 = *(const short8*)(bb);
        short8 b1 = *(const short8*)(bb + 128);
        short8 b2 = *(const short8*)(bb + 256);
        short8 b3 = *(const short8*)(bb + 384);

        float wvv[8] = {W0.x, W0.y, W0.z, W0.w, W1.x, W1.y, W1.z, W1.w};
        float p0[8];
        #pragma unroll
        for (int e = 0; e < 8; ++e) {
            float x = c + wvv[e];
            x = fmaxf(x, GAT_ALPHA * x);
            float p = __builtin_amdgcn_exp2f(x);
            p = (m0 & (1u << e)) ? p : 0.f;
            den += p; p0[e] = p;
        }
        short8 af = pack8_bf16(p0);

        acc0 = __builtin_amdgcn_mfma_f32_16x16x32_bf16(af, b0, acc0, 0, 0, 0);
        acc1 = __builtin_amdgcn_mfma_f32_16x16x32_bf16(af, b1, acc1, 0, 0, 0);
        acc2 = __builtin_amdgcn_mfma_f32_16x16x32_bf16(af, b2, acc2, 0, 0, 0);
        acc3 = __builtin_amdgcn_mfma_f32_16x16x32_bf16(af, b3, acc3, 0, 0, 0);
    }

    // reduce den over kg (lanes il, il+16, il+32, il+48)
    den += __shfl_xor(den, 16);
    den += __shfl_xor(den, 32);

    __syncthreads();   // all bmlds reads done; safe to overlay smem

    if (kg == 0) dens[wv][il] = den;
    #pragma unroll
    for (int q = 0; q < 4; ++q) {
        nums[wv][kg * 4 + q][0 * 16 + il] = acc0[q];
        nums[wv][kg * 4 + q][1 * 16 + il] = acc1[q];
        nums[wv][kg * 4 + q][2 * 16 + il] = acc2[q];
        nums[wv][kg * 4 + q][3 * 16 + il] = acc3[q];
    }
    __syncthreads();

    #pragma unroll
    for (int k = 0; k < 2; ++k) {
        const int idx = k * 512 + t;
        const int rr = idx >> 6, cc = idx & 63;
        float s = 0.f, dd = 0.f;
        #pragma unroll
        for (int w8 = 0; w8 < 8; ++w8) { s += nums[w8][rr][cc]; dd += dens[w8][rr]; }
        float val = s / dd + bias[cc];
        out[(size_t)(r0 + rr) * D_OUT + cc] =
            val > 0.f ? val : (__builtin_amdgcn_exp2f(val * LOG2E) - 1.f);
    }
}

extern "C" void kernel_launch(void* const* d_in, const int* in_sizes, int n_in,
                              void* d_out, int out_size, void* d_ws, size_t ws_size,
                              hipStream_t stream) {
    const float* h   = (const float*)d_in[0];
    const int*   adj = (const int*)d_in[1];
    const float* w   = (const float*)d_in[2];
    const float* a   = (const float*)d_in[3];
    const float* b   = (const float*)d_in[4];
    float* out = (float*)d_out;

    char* ws = (char*)d_ws;
    unsigned short* whB = (unsigned short*)ws;                        // 1 MB
    float* wh1p = (float*)(ws + (size_t)D_OUT * NN * 2);              // 32 KB
    float* wh2p = (float*)(ws + (size_t)D_OUT * NN * 2 + NN * 4);     // 32 KB

    gat_prep<<<NN / 16, 256, 0, stream>>>(h, w, a, whB, wh1p, wh2p);
    gat_fused<<<NN / 16, 512, 0, stream>>>(adj, whB, wh1p, wh2p, b, out);
}

// Round 12
// 76.197 us; speedup vs baseline: 1.1720x; 1.1720x over previous
//
#include <hip/hip_runtime.h>
#include <hip/hip_bf16.h>

#define NN 8192
#define D_IN 128
#define D_OUT 64
#define GAT_ALPHA 0.2f
#define LOG2E 1.4426950408889634f

typedef __attribute__((ext_vector_type(4))) float f32x4;
typedef __attribute__((ext_vector_type(8))) short short8;

static __device__ __forceinline__ unsigned short f32_bf16(float f) {
    unsigned u = __builtin_bit_cast(unsigned, f);
    u += 0x7fffu + ((u >> 16) & 1u);   // round-to-nearest-even
    return (unsigned short)(u >> 16);
}

// ---- Kernel 1: wh = h@w; wh1p/wh2p (x log2e); whB = K-blocked bf16 wh^T ----
// whB[j>>3][dim][j&7]: element (dim, j) at whB[(j>>3)*512 + dim*8 + (j&7)]
__global__ __launch_bounds__(256) void gat_prep(
    const float* __restrict__ h, const float* __restrict__ w,
    const float* __restrict__ a,
    unsigned short* __restrict__ whB, float* __restrict__ wh1p,
    float* __restrict__ wh2p)
{
    __shared__ float hs[16 * 128];
    __shared__ float whs[16][64];
    const int t = threadIdx.x;
    const int i0 = blockIdx.x * 16;

    const float* hsrc = h + (size_t)i0 * D_IN;
    *(float4*)(hs + t * 8)     = *(const float4*)(hsrc + t * 8);
    *(float4*)(hs + t * 8 + 4) = *(const float4*)(hsrc + t * 8 + 4);
    __syncthreads();

    const int r  = t >> 4;          // local row 0..15
    const int og = (t & 15) * 4;    // 4 output dims
    f32x4 acc = {0.f, 0.f, 0.f, 0.f};
    for (int k = 0; k < D_IN; ++k) {
        float hv = hs[r * 128 + k];
        float4 wv = *(const float4*)(w + k * D_OUT + og);
        acc[0] += hv * wv.x; acc[1] += hv * wv.y;
        acc[2] += hv * wv.z; acc[3] += hv * wv.w;
    }
    whs[r][og]     = acc[0];
    whs[r][og + 1] = acc[1];
    whs[r][og + 2] = acc[2];
    whs[r][og + 3] = acc[3];

    float p1 = acc[0]*a[og] + acc[1]*a[og+1] + acc[2]*a[og+2] + acc[3]*a[og+3];
    float p2 = acc[0]*a[64+og] + acc[1]*a[64+og+1] + acc[2]*a[64+og+2] + acc[3]*a[64+og+3];
    #pragma unroll
    for (int m = 1; m < 16; m <<= 1) {
        p1 += __shfl_xor(p1, m);
        p2 += __shfl_xor(p2, m);
    }
    if ((t & 15) == 0) {
        wh1p[i0 + r] = p1 * LOG2E;
        wh2p[i0 + r] = p2 * LOG2E;
    }
    __syncthreads();

    {
        const int half = t >> 7;         // which 8-row group
        const int dim  = (t >> 1) & 63;
        const int e0   = (t & 1) * 4;
        ushort4 v;
        v.x = f32_bf16(whs[half * 8 + e0 + 0][dim]);
        v.y = f32_bf16(whs[half * 8 + e0 + 1][dim]);
        v.z = f32_bf16(whs[half * 8 + e0 + 2][dim]);
        v.w = f32_bf16(whs[half * 8 + e0 + 3][dim]);
        *(ushort4*)(whB + (size_t)(i0 / 8 + half) * 512 + dim * 8 + e0) = v;
    }
}

// ---- Kernel 2: per-wave private pipeline; reg loads pipelined R=2 so the
// vmcnt FIFO is never force-drained; adj stages keep S=3 depth in flight ----
#define AF_LANE(PV, AD, IDX)                                                    \
    do { float x_ = c + (PV);                                                   \
         x_ = fmaxf(x_, GAT_ALPHA * x_);                                        \
         float p_ = __builtin_amdgcn_exp2f(x_);                                 \
         p_ = (AD) ? p_ : 0.f; den += p_;                                       \
         af[IDX] = (short)f32_bf16(p_); } while (0)

#define REG_LOAD(nn, B0,B1,B2,B3, W0,W1) do {                                   \
    const int jr_ = jbase + (nn) * 32;                                          \
    W0 = *(const float4*)(wh2p + jr_ + kg * 8);                                 \
    W1 = *(const float4*)(wh2p + jr_ + kg * 8 + 4);                             \
    const unsigned short* bb_ = whB + (size_t)(jr_ / 8 + kg) * 512 + il * 8;    \
    B0 = *(const short8*)(bb_);                                                 \
    B1 = *(const short8*)(bb_ + 128);                                           \
    B2 = *(const short8*)(bb_ + 256);                                           \
    B3 = *(const short8*)(bb_ + 384);                                           \
} while (0)

#define ITER(n, WN, DO_REG, DO_STAGE, B0,B1,B2,B3, W0,W1) do {                  \
    short8 nb0 = {}, nb1 = {}, nb2 = {}, nb3 = {};                              \
    float4 nw0 = {}, nw1 = {};                                                  \
    if (DO_REG) REG_LOAD((n) + 2, nb0, nb1, nb2, nb3, nw0, nw1);                \
    __builtin_amdgcn_sched_barrier(0);                                          \
    if (DO_STAGE) {                                                             \
        const int off_ = ((n) + 3) * 32;                                        \
        __builtin_amdgcn_global_load_lds(                                       \
            (const __attribute__((address_space(1))) void*)(g0 + off_),         \
            (__attribute__((address_space(3))) void*)&adjs[wv][((n)+3) & 3][0], \
            16, 0, 0);                                                          \
        __builtin_amdgcn_global_load_lds(                                       \
            (const __attribute__((address_space(1))) void*)(g1 + off_),         \
            (__attribute__((address_space(3))) void*)&adjs[wv][((n)+3) & 3][64],\
            16, 0, 0);                                                          \
    }                                                                           \
    asm volatile("s_waitcnt vmcnt(" #WN ")" ::: "memory");                      \
    __builtin_amdgcn_sched_barrier(0);                                          \
    const int4* base_ = &adjs[wv][(n) & 3][0];                                  \
    int4 ad0 = base_[uA];                                                       \
    int4 ad1 = base_[uB];                                                       \
    short8 af;                                                                  \
    AF_LANE(W0.x, ad0.x, 0); AF_LANE(W0.y, ad0.y, 1);                           \
    AF_LANE(W0.z, ad0.z, 2); AF_LANE(W0.w, ad0.w, 3);                           \
    AF_LANE(W1.x, ad1.x, 4); AF_LANE(W1.y, ad1.y, 5);                           \
    AF_LANE(W1.z, ad1.z, 6); AF_LANE(W1.w, ad1.w, 7);                           \
    acc0 = __builtin_amdgcn_mfma_f32_16x16x32_bf16(af, B0, acc0, 0, 0, 0);      \
    acc1 = __builtin_amdgcn_mfma_f32_16x16x32_bf16(af, B1, acc1, 0, 0, 0);      \
    acc2 = __builtin_amdgcn_mfma_f32_16x16x32_bf16(af, B2, acc2, 0, 0, 0);      \
    acc3 = __builtin_amdgcn_mfma_f32_16x16x32_bf16(af, B3, acc3, 0, 0, 0);      \
    if (DO_REG) { B0 = nb0; B1 = nb1; B2 = nb2; B3 = nb3; W0 = nw0; W1 = nw1; } \
} while (0)

__global__ __launch_bounds__(256) void gat_main(
    const int* __restrict__ adj, const unsigned short* __restrict__ whB,
    const float* __restrict__ wh1p, const float* __restrict__ wh2p,
    const float* __restrict__ bias, float* __restrict__ out)
{
    __shared__ int4  adjs[4][4][128];     // [wave][depth][16B unit] = 32 KB
    __shared__ float nums4[4][16][64];    // 16 KB
    __shared__ float dens4[4][16];

    const int t    = threadIdx.x;
    const int wv   = t >> 6;
    const int lane = t & 63;
    const int il   = lane & 15;
    const int kg   = lane >> 4;
    const int i0   = blockIdx.x * 16;
    const int jbase = wv * 2048;

    const float c = wh1p[i0 + il];

    // staging geometry: lane l -> row l>>3, chunk ((l&7) - row) & 7
    // (inverse of LDS unit(r,c) = r*8 + ((c+r)&7))
    const int srow = lane >> 3;
    const int scol = ((lane & 7) + 8 - srow) & 7;
    const int* g0 = adj + (size_t)(i0 + srow) * NN + jbase + scol * 4;
    const int* g1 = adj + (size_t)(i0 + 8 + srow) * NN + jbase + scol * 4;

    // swizzled read units for this lane (invariant across tiles)
    const int uA = il * 8 + ((2 * kg + il) & 7);
    const int uB = il * 8 + ((2 * kg + 1 + il) & 7);

    f32x4 acc0 = {0,0,0,0}, acc1 = {0,0,0,0}, acc2 = {0,0,0,0}, acc3 = {0,0,0,0};
    float den = 0.f;

    // prologue: stage tiles 0,1,2 (6 VMEM), then reg-preload tiles 0,1 (12 VMEM)
    #pragma unroll
    for (int tl = 0; tl < 3; ++tl) {
        const int off = tl * 32;
        __builtin_amdgcn_global_load_lds(
            (const __attribute__((address_space(1))) void*)(g0 + off),
            (__attribute__((address_space(3))) void*)&adjs[wv][tl][0], 16, 0, 0);
        __builtin_amdgcn_global_load_lds(
            (const __attribute__((address_space(1))) void*)(g1 + off),
            (__attribute__((address_space(3))) void*)&adjs[wv][tl][64], 16, 0, 0);
    }
    short8 bA0, bA1, bA2, bA3; float4 wA0, wA1;   // even tiles
    short8 bB0, bB1, bB2, bB3; float4 wB0, wB1;   // odd tiles
    REG_LOAD(0, bA0, bA1, bA2, bA3, wA0, wA1);
    REG_LOAD(1, bB0, bB1, bB2, bB3, wB0, wB1);

    // peeled head (exact newer-op counts at each wait)
    ITER(0, 24, 1, 1, bA0, bA1, bA2, bA3, wA0, wA1);
    ITER(1, 30, 1, 1, bB0, bB1, bB2, bB3, wB0, wB1);
    ITER(2, 36, 1, 1, bA0, bA1, bA2, bA3, wA0, wA1);
    ITER(3, 24, 1, 1, bB0, bB1, bB2, bB3, wB0, wB1);

    #pragma clang loop unroll_count(1)
    for (int n = 4; n <= 58; n += 2) {
        ITER(n,     24, 1, 1, bA0, bA1, bA2, bA3, wA0, wA1);
        ITER(n + 1, 24, 1, 1, bB0, bB1, bB2, bB3, wB0, wB1);
    }

    ITER(60, 24, 1, 1, bA0, bA1, bA2, bA3, wA0, wA1);
    ITER(61, 22, 1, 0, bB0, bB1, bB2, bB3, wB0, wB1);
    ITER(62, 14, 0, 0, bA0, bA1, bA2, bA3, wA0, wA1);
    ITER(63,  6, 0, 0, bB0, bB1, bB2, bB3, wB0, wB1);

    // deterministic cross-wave reduction
    den += __shfl_xor(den, 16);
    den += __shfl_xor(den, 32);
    if (kg == 0) dens4[wv][il] = den;

    #pragma unroll
    for (int q = 0; q < 4; ++q) {
        nums4[wv][kg * 4 + q][0 * 16 + il] = acc0[q];
        nums4[wv][kg * 4 + q][1 * 16 + il] = acc1[q];
        nums4[wv][kg * 4 + q][2 * 16 + il] = acc2[q];
        nums4[wv][kg * 4 + q][3 * 16 + il] = acc3[q];
    }
    __syncthreads();

    for (int idx = t; idx < 16 * 64; idx += 256) {
        const int rr = idx >> 6, cc = idx & 63;
        float s = 0.f, d = 0.f;
        #pragma unroll
        for (int wq = 0; wq < 4; ++wq) { s += nums4[wq][rr][cc]; d += dens4[wq][rr]; }
        float val = s / d + bias[cc];
        out[(size_t)(i0 + rr) * D_OUT + cc] =
            val > 0.f ? val : (__builtin_amdgcn_exp2f(val * LOG2E) - 1.f);
    }
}

extern "C" void kernel_launch(void* const* d_in, const int* in_sizes, int n_in,
                              void* d_out, int out_size, void* d_ws, size_t ws_size,
                              hipStream_t stream) {
    const float* h   = (const float*)d_in[0];
    const int*   adj = (const int*)d_in[1];
    const float* w   = (const float*)d_in[2];
    const float* a   = (const float*)d_in[3];
    const float* b   = (const float*)d_in[4];
    float* out = (float*)d_out;

    char* ws = (char*)d_ws;
    unsigned short* whB = (unsigned short*)ws;                       // 1 MB
    float* wh1p = (float*)(ws + (size_t)D_OUT * NN * 2);             // 32 KB
    float* wh2p = (float*)(ws + (size_t)D_OUT * NN * 2 + NN * 4);    // 32 KB

    gat_prep<<<NN / 16, 256, 0, stream>>>(h, w, a, whB, wh1p, wh2p);
    gat_main<<<NN / 16, 256, 0, stream>>>(adj, whB, wh1p, wh2p, b, out);
}